// Round 3
// baseline (1387.515 us; speedup 1.0000x reference)
//
#include <hip/hip_runtime.h>

// Chebyshev GCN: out = sum_k S_k @ X @ W_k + bias, computed as
//   per support k: build CSR of S_k on device, then per output row r:
//     t[:] = sum_{edges into r} val * X[col, :]   (register gather, no atomics)
//     out[r,:] (+)= t @ W_k  (+ bias on k==0)     (readlane x W-in-VGPR)
// Scratch: packed edges E*8B + counts/offsets/cursor 3*N*4B ~= 14 MB.

__global__ __launch_bounds__(256) void zero_kernel(int* __restrict__ p, int n) {
  int i = blockIdx.x * 256 + threadIdx.x;
  if (i < n) p[i] = 0;
}

__global__ __launch_bounds__(256) void hist_kernel(
    const int* __restrict__ rows, int* __restrict__ counts, int E) {
  int i = blockIdx.x * 256 + threadIdx.x;
  if (i < E) atomicAdd(&counts[rows[i]], 1);
}

// per-block sum of 512 counts -> blockSums[b]
__global__ __launch_bounds__(512) void scanA_kernel(
    const int* __restrict__ counts, int* __restrict__ blockSums, int N) {
  __shared__ int red[8];
  int i = blockIdx.x * 512 + threadIdx.x;
  int v = (i < N) ? counts[i] : 0;
#pragma unroll
  for (int off = 32; off; off >>= 1) v += __shfl_down(v, off);
  if ((threadIdx.x & 63) == 0) red[threadIdx.x >> 6] = v;
  __syncthreads();
  if (threadIdx.x == 0) {
    int s = 0;
#pragma unroll
    for (int w = 0; w < 8; ++w) s += red[w];
    blockSums[blockIdx.x] = s;
  }
}

// exclusive scan of blockSums[NB] (NB <= 256), single block
__global__ __launch_bounds__(256) void scanB_kernel(int* __restrict__ bs, int NB) {
  __shared__ int s[2][256];
  int t = threadIdx.x;
  int v = (t < NB) ? bs[t] : 0;
  s[0][t] = v;
  __syncthreads();
  int cur = 0;
  for (int off = 1; off < 256; off <<= 1) {
    int nv = s[cur][t] + ((t >= off) ? s[cur][t - off] : 0);
    s[cur ^ 1][t] = nv;
    cur ^= 1;
    __syncthreads();
  }
  if (t < NB) bs[t] = s[cur][t] - v;  // exclusive
}

// block-local inclusive scan of 512 counts + block offset -> offsets, cursor
__global__ __launch_bounds__(512) void scanC_kernel(
    const int* __restrict__ counts, const int* __restrict__ bs,
    int* __restrict__ offsets, int* __restrict__ cursor, int N) {
  __shared__ int s[2][512];
  int t = threadIdx.x;
  int i = blockIdx.x * 512 + t;
  int v = (i < N) ? counts[i] : 0;
  s[0][t] = v;
  __syncthreads();
  int cur = 0;
  for (int off = 1; off < 512; off <<= 1) {
    int nv = s[cur][t] + ((t >= off) ? s[cur][t - off] : 0);
    s[cur ^ 1][t] = nv;
    cur ^= 1;
    __syncthreads();
  }
  int excl = s[cur][t] - v + bs[blockIdx.x];
  if (i < N) { offsets[i] = excl; cursor[i] = excl; }
}

__global__ __launch_bounds__(256) void reorder_kernel(
    const int* __restrict__ rows, const int* __restrict__ cols,
    const float* __restrict__ vals, int* __restrict__ cursor,
    int2* __restrict__ packed, int E) {
  int i = blockIdx.x * 256 + threadIdx.x;
  if (i < E) {
    int r = rows[i];
    int pos = atomicAdd(&cursor[r], 1);
    packed[pos] = make_int2(cols[i], __float_as_int(vals[i]));
  }
}

// one wave per 2 rows; lane = feature. W_k column held in 64 VGPRs.
__global__ __launch_bounds__(256) void gather_kernel(
    const int2* __restrict__ packed, const int* __restrict__ offsets,
    const int* __restrict__ counts, const float* __restrict__ X,
    const float* __restrict__ Wk, const float* __restrict__ bias,
    float* __restrict__ out, int N, int first) {
  const int lane = threadIdx.x & 63;
  const int gw = blockIdx.x * 4 + (threadIdx.x >> 6);
  const int r0 = gw * 2;
  if (r0 >= N) return;
  const int r1 = r0 + 1;
  const bool has1 = (r1 < N);

  float w[64];
#pragma unroll
  for (int i = 0; i < 64; ++i) w[i] = Wk[i * 64 + lane];

  const int s0 = offsets[r0], c0 = counts[r0];
  const int s1 = has1 ? offsets[r1] : 0;
  const int c1 = has1 ? counts[r1] : 0;
  float acc0 = 0.f, acc1 = 0.f;
  const int m = max(c0, c1);
  for (int j = 0; j < m; ++j) {
    if (j < c0) {
      int2 p = packed[s0 + j];
      acc0 += __int_as_float(p.y) * X[(size_t)p.x * 64 + lane];
    }
    if (j < c1) {
      int2 p = packed[s1 + j];
      acc1 += __int_as_float(p.y) * X[(size_t)p.x * 64 + lane];
    }
  }

  float o0, o1;
  if (first) {
    o0 = bias[lane];
    o1 = o0;
  } else {
    o0 = out[(size_t)r0 * 64 + lane];
    o1 = has1 ? out[(size_t)r1 * 64 + lane] : 0.f;
  }
  float p00 = 0, p01 = 0, p02 = 0, p03 = 0;
  float p10 = 0, p11 = 0, p12 = 0, p13 = 0;
#pragma unroll
  for (int i = 0; i < 16; ++i) {
    p00 += __int_as_float(__builtin_amdgcn_readlane(__float_as_int(acc0), 4 * i + 0)) * w[4 * i + 0];
    p01 += __int_as_float(__builtin_amdgcn_readlane(__float_as_int(acc0), 4 * i + 1)) * w[4 * i + 1];
    p02 += __int_as_float(__builtin_amdgcn_readlane(__float_as_int(acc0), 4 * i + 2)) * w[4 * i + 2];
    p03 += __int_as_float(__builtin_amdgcn_readlane(__float_as_int(acc0), 4 * i + 3)) * w[4 * i + 3];
    p10 += __int_as_float(__builtin_amdgcn_readlane(__float_as_int(acc1), 4 * i + 0)) * w[4 * i + 0];
    p11 += __int_as_float(__builtin_amdgcn_readlane(__float_as_int(acc1), 4 * i + 1)) * w[4 * i + 1];
    p12 += __int_as_float(__builtin_amdgcn_readlane(__float_as_int(acc1), 4 * i + 2)) * w[4 * i + 2];
    p13 += __int_as_float(__builtin_amdgcn_readlane(__float_as_int(acc1), 4 * i + 3)) * w[4 * i + 3];
  }
  o0 += (p00 + p01) + (p02 + p03);
  out[(size_t)r0 * 64 + lane] = o0;
  if (has1) {
    o1 += (p10 + p11) + (p12 + p13);
    out[(size_t)r1 * 64 + lane] = o1;
  }
}

extern "C" void kernel_launch(void* const* d_in, const int* in_sizes, int n_in,
                              void* d_out, int out_size, void* d_ws, size_t ws_size,
                              hipStream_t stream) {
  const float* X    = (const float*)d_in[0];  // [N, 64]
  const int*   rows = (const int*)d_in[1];    // [3, E]
  const int*   cols = (const int*)d_in[2];    // [3, E]
  const float* vals = (const float*)d_in[3];  // [3, E]
  const float* W    = (const float*)d_in[4];  // [192, 64]
  const float* bias = (const float*)d_in[5];  // [64]
  float* out = (float*)d_out;                 // [N, 64] f32

  const int N = in_sizes[0] / 64;
  const int E = in_sizes[1] / 3;

  char* wp = (char*)d_ws;
  int2* packed  = (int2*)wp;            wp += (size_t)E * 8;
  int* counts   = (int*)wp;             wp += (size_t)N * 4;
  int* offsets  = (int*)wp;             wp += (size_t)N * 4;
  int* cursor   = (int*)wp;             wp += (size_t)N * 4;
  int* blockSums = (int*)wp;

  const int NB = (N + 511) / 512;       // 196 for N=100000 (<=256 req'd by scanB)
  const int zeroBlocks = (N + 255) / 256;
  const int eBlocks = (E + 255) / 256;
  const int gatherBlocks = ((N + 1) / 2 + 3) / 4;

  for (int k = 0; k < 3; ++k) {
    const int* rk = rows + (size_t)k * E;
    zero_kernel<<<zeroBlocks, 256, 0, stream>>>(counts, N);
    hist_kernel<<<eBlocks, 256, 0, stream>>>(rk, counts, E);
    scanA_kernel<<<NB, 512, 0, stream>>>(counts, blockSums, N);
    scanB_kernel<<<1, 256, 0, stream>>>(blockSums, NB);
    scanC_kernel<<<NB, 512, 0, stream>>>(counts, blockSums, offsets, cursor, N);
    reorder_kernel<<<eBlocks, 256, 0, stream>>>(
        rk, cols + (size_t)k * E, vals + (size_t)k * E, cursor, packed, E);
    gather_kernel<<<gatherBlocks, 256, 0, stream>>>(
        packed, offsets, counts, X, W + (size_t)k * 64 * 64, bias, out, N,
        k == 0 ? 1 : 0);
  }
}

// Round 6
// 939.674 us; speedup vs baseline: 1.4766x; 1.4766x over previous
//
#include <hip/hip_runtime.h>

// Chebyshev GCN: out = sum_k S_k @ X @ W_k + bias.
// Device-built CSR per support (fused across supports when ws allows), then
// row-gather with NO atomics:
//   per row r: t = sum_e val_e * X[col_e, :]  (batched packed load + readlane
//              broadcast -> independent X loads, 4-way unrolled)
//   out[r,:] (+)= t @ W_k (+bias on k==0)     (readlane x W-column-in-VGPR)

__global__ __launch_bounds__(256) void zero_kernel(int* __restrict__ p, int n) {
  int i = blockIdx.x * 256 + threadIdx.x;
  if (i < n) p[i] = 0;
}

// histogram of destination rows; supports laid out [nsup, E] contiguous
__global__ __launch_bounds__(256) void hist_kernel(
    const int* __restrict__ rows, int* __restrict__ counts,
    int E, int nsup, int N) {
  int i = blockIdx.x * 256 + threadIdx.x;
  if (i < E * nsup) {
    int k = (i >= E) + (i >= 2 * E);
    atomicAdd(&counts[k * N + rows[i]], 1);
  }
}

// per-block (2048 elems) sum -> blockSums
__global__ __launch_bounds__(512) void scanA_kernel(
    const int* __restrict__ counts, int* __restrict__ blockSums, int M) {
  __shared__ int wsum[8];
  const int t = threadIdx.x;
  const int i0 = blockIdx.x * 2048 + t * 4;
  int s = 0;
  if (i0 + 3 < M) {
    int4 c = *reinterpret_cast<const int4*>(counts + i0);
    s = c.x + c.y + c.z + c.w;
  } else {
#pragma unroll
    for (int u = 0; u < 4; ++u)
      if (i0 + u < M) s += counts[i0 + u];
  }
#pragma unroll
  for (int off = 32; off; off >>= 1) s += __shfl_down(s, off);
  if ((t & 63) == 0) wsum[t >> 6] = s;
  __syncthreads();
  if (t == 0) {
    int tot = 0;
#pragma unroll
    for (int w = 0; w < 8; ++w) tot += wsum[w];
    blockSums[blockIdx.x] = tot;
  }
}

// exclusive scan of blockSums[NB], NB <= 256, one block
__global__ __launch_bounds__(256) void scanB_kernel(int* __restrict__ bs, int NB) {
  __shared__ int s[2][256];
  int t = threadIdx.x;
  int v = (t < NB) ? bs[t] : 0;
  s[0][t] = v;
  __syncthreads();
  int cur = 0;
  for (int off = 1; off < 256; off <<= 1) {
    int nv = s[cur][t] + ((t >= off) ? s[cur][t - off] : 0);
    s[cur ^ 1][t] = nv;
    cur ^= 1;
    __syncthreads();
  }
  if (t < NB) bs[t] = s[cur][t] - v;
}

// full exclusive scan -> offsets, cursor
__global__ __launch_bounds__(512) void scanC_kernel(
    const int* __restrict__ counts, const int* __restrict__ bs,
    int* __restrict__ offsets, int* __restrict__ cursor, int M) {
  __shared__ int wsum[8];
  const int t = threadIdx.x;
  const int lane = t & 63;
  const int wid = t >> 6;
  const int i0 = blockIdx.x * 2048 + t * 4;
  int c0 = 0, c1 = 0, c2 = 0, c3 = 0;
  if (i0 + 3 < M) {
    int4 c = *reinterpret_cast<const int4*>(counts + i0);
    c0 = c.x; c1 = c.y; c2 = c.z; c3 = c.w;
  } else {
    if (i0 + 0 < M) c0 = counts[i0 + 0];
    if (i0 + 1 < M) c1 = counts[i0 + 1];
    if (i0 + 2 < M) c2 = counts[i0 + 2];
  }
  int s = c0 + c1 + c2 + c3;
  int inc = s;
#pragma unroll
  for (int off = 1; off < 64; off <<= 1) {
    int v = __shfl_up(inc, off);
    if (lane >= off) inc += v;
  }
  if (lane == 63) wsum[wid] = inc;
  __syncthreads();
  int wbase = 0;
#pragma unroll
  for (int w = 0; w < 8; ++w) wbase += (w < wid) ? wsum[w] : 0;
  int excl = bs[blockIdx.x] + wbase + (inc - s);
  int o0 = excl, o1 = o0 + c0, o2 = o1 + c1, o3 = o2 + c2;
  if (i0 + 0 < M) { offsets[i0 + 0] = o0; cursor[i0 + 0] = o0; }
  if (i0 + 1 < M) { offsets[i0 + 1] = o1; cursor[i0 + 1] = o1; }
  if (i0 + 2 < M) { offsets[i0 + 2] = o2; cursor[i0 + 2] = o2; }
  if (i0 + 3 < M) { offsets[i0 + 3] = o3; cursor[i0 + 3] = o3; }
}

__global__ __launch_bounds__(256) void reorder_kernel(
    const int* __restrict__ rows, const int* __restrict__ cols,
    const float* __restrict__ vals, int* __restrict__ cursor,
    int2* __restrict__ packed, int E, int nsup, int N) {
  int i = blockIdx.x * 256 + threadIdx.x;
  if (i < E * nsup) {
    int k = (i >= E) + (i >= 2 * E);
    int r = rows[i];
    int pos = atomicAdd(&cursor[k * N + r], 1);
    packed[pos] = make_int2(cols[i], __float_as_int(vals[i]));
  }
}

// one wave per row; lane = feature; W_k column in 64 VGPRs.
__global__ __launch_bounds__(256) void gather_kernel(
    const int2* __restrict__ packed, const int* __restrict__ offs,
    const int* __restrict__ cnts, const float* __restrict__ X,
    const float* __restrict__ Wk, const float* __restrict__ bias,
    float* __restrict__ out, int N, int first) {
  const int lane = threadIdx.x & 63;
  float w[64];
#pragma unroll
  for (int i = 0; i < 64; ++i) w[i] = Wk[i * 64 + lane];
  const int gw0 = (blockIdx.x * 256 + threadIdx.x) >> 6;
  const int nw = (gridDim.x * 256) >> 6;
  for (int r = gw0; r < N; r += nw) {
    const int base = offs[r];
    const int c = cnts[r];
    float acc = 0.f;
    for (int j0 = 0; j0 < c; j0 += 64) {
      // one coalesced 512B load covers up to 64 edges (buffer padded by 64)
      int2 p = packed[base + j0 + lane];
      const int lim = min(64, c - j0);
      float a0 = 0.f, a1 = 0.f, a2 = 0.f, a3 = 0.f;
      int j = 0;
      for (; j + 3 < lim; j += 4) {
        int col0 = __builtin_amdgcn_readlane(p.x, j + 0);
        int col1 = __builtin_amdgcn_readlane(p.x, j + 1);
        int col2 = __builtin_amdgcn_readlane(p.x, j + 2);
        int col3 = __builtin_amdgcn_readlane(p.x, j + 3);
        float v0 = __int_as_float(__builtin_amdgcn_readlane(p.y, j + 0));
        float v1 = __int_as_float(__builtin_amdgcn_readlane(p.y, j + 1));
        float v2 = __int_as_float(__builtin_amdgcn_readlane(p.y, j + 2));
        float v3 = __int_as_float(__builtin_amdgcn_readlane(p.y, j + 3));
        float x0 = X[(size_t)col0 * 64 + lane];
        float x1 = X[(size_t)col1 * 64 + lane];
        float x2 = X[(size_t)col2 * 64 + lane];
        float x3 = X[(size_t)col3 * 64 + lane];
        a0 = fmaf(v0, x0, a0);
        a1 = fmaf(v1, x1, a1);
        a2 = fmaf(v2, x2, a2);
        a3 = fmaf(v3, x3, a3);
      }
      for (; j < lim; ++j) {
        int col = __builtin_amdgcn_readlane(p.x, j);
        float v = __int_as_float(__builtin_amdgcn_readlane(p.y, j));
        a0 = fmaf(v, X[(size_t)col * 64 + lane], a0);
      }
      acc += (a0 + a1) + (a2 + a3);
    }
    // epilogue: out[r][lane] (+)= sum_i acc_bcast[i] * w[i]
    float o = first ? bias[lane] : out[(size_t)r * 64 + lane];
    const int ai = __float_as_int(acc);
    float p0 = 0.f, p1 = 0.f, p2 = 0.f, p3 = 0.f;
#pragma unroll
    for (int i = 0; i < 16; ++i) {
      p0 = fmaf(__int_as_float(__builtin_amdgcn_readlane(ai, 4 * i + 0)), w[4 * i + 0], p0);
      p1 = fmaf(__int_as_float(__builtin_amdgcn_readlane(ai, 4 * i + 1)), w[4 * i + 1], p1);
      p2 = fmaf(__int_as_float(__builtin_amdgcn_readlane(ai, 4 * i + 2)), w[4 * i + 2], p2);
      p3 = fmaf(__int_as_float(__builtin_amdgcn_readlane(ai, 4 * i + 3)), w[4 * i + 3], p3);
    }
    o += (p0 + p1) + (p2 + p3);
    out[(size_t)r * 64 + lane] = o;
  }
}

extern "C" void kernel_launch(void* const* d_in, const int* in_sizes, int n_in,
                              void* d_out, int out_size, void* d_ws, size_t ws_size,
                              hipStream_t stream) {
  const float* X    = (const float*)d_in[0];  // [N, 64]
  const int*   rows = (const int*)d_in[1];    // [3, E]
  const int*   cols = (const int*)d_in[2];    // [3, E]
  const float* vals = (const float*)d_in[3];  // [3, E]
  const float* W    = (const float*)d_in[4];  // [192, 64]
  const float* bias = (const float*)d_in[5];  // [64]
  float* out = (float*)d_out;                 // [N, 64] f32

  const int N = in_sizes[0] / 64;
  const int E = in_sizes[1] / 3;

  const size_t padPacked = 64 * sizeof(int2);
  const size_t needFused = (size_t)3 * E * 8 + padPacked + 3 * ((size_t)3 * N * 4) + 2048;
  const bool fused = ws_size >= needFused;
  const int nsup = fused ? 3 : 1;
  const int M = nsup * N;

  char* wp = (char*)d_ws;
  int2* packed   = (int2*)wp;  wp += (size_t)nsup * E * 8 + padPacked;
  int* counts    = (int*)wp;   wp += (size_t)M * 4;
  int* offsets   = (int*)wp;   wp += (size_t)M * 4;
  int* cursor    = (int*)wp;   wp += (size_t)M * 4;
  int* blockSums = (int*)wp;

  const int NB = (M + 2047) / 2048;          // 147 fused / 49 per-support
  const int zB = (M + 255) / 256;
  const int eB = (E * nsup + 255) / 256;
  const int gatherBlocks = 4096;

  if (fused) {
    zero_kernel<<<zB, 256, 0, stream>>>(counts, M);
    hist_kernel<<<eB, 256, 0, stream>>>(rows, counts, E, 3, N);
    scanA_kernel<<<NB, 512, 0, stream>>>(counts, blockSums, M);
    scanB_kernel<<<1, 256, 0, stream>>>(blockSums, NB);
    scanC_kernel<<<NB, 512, 0, stream>>>(counts, blockSums, offsets, cursor, M);
    reorder_kernel<<<eB, 256, 0, stream>>>(rows, cols, vals, cursor, packed, E, 3, N);
    for (int k = 0; k < 3; ++k)
      gather_kernel<<<gatherBlocks, 256, 0, stream>>>(
          packed, offsets + (size_t)k * N, counts + (size_t)k * N, X,
          W + (size_t)k * 64 * 64, bias, out, N, k == 0 ? 1 : 0);
  } else {
    for (int k = 0; k < 3; ++k) {
      zero_kernel<<<zB, 256, 0, stream>>>(counts, M);
      hist_kernel<<<eB, 256, 0, stream>>>(rows + (size_t)k * E, counts, E, 1, N);
      scanA_kernel<<<NB, 512, 0, stream>>>(counts, blockSums, M);
      scanB_kernel<<<1, 256, 0, stream>>>(blockSums, NB);
      scanC_kernel<<<NB, 512, 0, stream>>>(counts, blockSums, offsets, cursor, M);
      reorder_kernel<<<eB, 256, 0, stream>>>(
          rows + (size_t)k * E, cols + (size_t)k * E, vals + (size_t)k * E,
          cursor, packed, E, 1, N);
      gather_kernel<<<gatherBlocks, 256, 0, stream>>>(
          packed, offsets, counts, X, W + (size_t)k * 64 * 64, bias, out, N,
          k == 0 ? 1 : 0);
    }
  }
}